// Round 1
// baseline (881.902 us; speedup 1.0000x reference)
//
#include <hip/hip_runtime.h>
#include <hip/hip_bf16.h>
#include <math.h>

#define LSEQ 2048
#define NB 4
#define DM 1024
#define ZD 128
#define HD 2048
#define ND 16
#define NEXTD 256

typedef __bf16 bf16x8 __attribute__((ext_vector_type(8)));
typedef __bf16 bf16x4 __attribute__((ext_vector_type(4)));
typedef float f32x4 __attribute__((ext_vector_type(4)));

__device__ __forceinline__ float sigm(float x){ return 1.0f/(1.0f+expf(-x)); }
__device__ __forceinline__ float silu_(float x){ return x/(1.0f+expf(-x)); }
__device__ __forceinline__ float laplacef(float x){ return 0.5f*(1.0f+erff((x-0.70710678f)*2.5066282746f)); }

__device__ __forceinline__ void load_lds16(const __bf16* g, __bf16* l){
  __builtin_amdgcn_global_load_lds((const __attribute__((address_space(1))) void*)g,
                                   (__attribute__((address_space(3))) void*)l, 16, 0, 0);
}

// ---------------- weight fp32 -> bf16 ----------------
__global__ __launch_bounds__(256) void f2b(const float4* __restrict__ in, bf16x4* __restrict__ out, int n4){
  const int i = blockIdx.x*256 + threadIdx.x;
  if (i < n4){
    float4 v = in[i];
    bf16x4 o; o[0]=(__bf16)v.x; o[1]=(__bf16)v.y; o[2]=(__bf16)v.z; o[3]=(__bf16)v.w;
    out[i] = o;
  }
}

// ---------------- LayerNorm: one block per row of 1024 ----------------
__global__ __launch_bounds__(256) void ln_kernel(const float* __restrict__ x, const float* __restrict__ w,
                                                 const float* __restrict__ b, float* __restrict__ xn,
                                                 __bf16* __restrict__ xnb){
  const long row = blockIdx.x;
  const int tid = threadIdx.x;
  float4 v = ((const float4*)(x + row*DM))[tid];
  float s = v.x+v.y+v.z+v.w;
  float ss = v.x*v.x+v.y*v.y+v.z*v.z+v.w*v.w;
#pragma unroll
  for (int o=32;o>0;o>>=1){ s += __shfl_down(s,o); ss += __shfl_down(ss,o); }
  __shared__ float red[8];
  __shared__ float mv[2];
  const int wid2 = tid>>6, lane = tid&63;
  if (lane==0){ red[wid2]=s; red[4+wid2]=ss; }
  __syncthreads();
  if (tid==0){
    float ts = red[0]+red[1]+red[2]+red[3];
    float tss = red[4]+red[5]+red[6]+red[7];
    float mean = ts*(1.0f/DM);
    float var = tss*(1.0f/DM) - mean*mean;
    mv[0]=mean; mv[1]=rsqrtf(var + 1e-5f);
  }
  __syncthreads();
  const float mean=mv[0], rs=mv[1];
  float4 wv = ((const float4*)w)[tid];
  float4 bv = ((const float4*)b)[tid];
  float4 o;
  o.x=(v.x-mean)*rs*wv.x+bv.x;
  o.y=(v.y-mean)*rs*wv.y+bv.y;
  o.z=(v.z-mean)*rs*wv.z+bv.z;
  o.w=(v.w-mean)*rs*wv.w+bv.w;
  ((float4*)(xn + row*DM))[tid]=o;
  bf16x4 ob; ob[0]=(__bf16)o.x; ob[1]=(__bf16)o.y; ob[2]=(__bf16)o.z; ob[3]=(__bf16)o.w;
  ((bf16x4*)(xnb + row*DM))[tid]=ob;
}

// ---------------- EMA parameter precompute: i = d*16+n ----------------
__global__ __launch_bounds__(256) void ema_params_k(const float* __restrict__ de, const float* __restrict__ al,
                                                    const float* __restrict__ be, const float* __restrict__ ga,
                                                    float* __restrict__ qo, float* __restrict__ wo){
  const int i = blockIdx.x*256 + threadIdx.x;  // exactly D*ND threads
  const float p = sigm(de[i]);
  qo[i] = 1.0f - p*sigm(al[i]);
  wo[i] = p*be[i]*ga[i]*0.25f;   // scale = sqrt(1/16)
}

// ---------------- EMA recurrence, chunk of 128 outputs + 1024-step warmup ----------------
// s_n[l] = q_n s_n[l-1] + x[l];  out[l] = silu( sum_n w'_n s_n[l] + x[l]*omega )
__global__ __launch_bounds__(64) void ema_kernel(const float* __restrict__ xn, const float* __restrict__ qp,
                                                 const float* __restrict__ wp, const float* __restrict__ omega,
                                                 __bf16* __restrict__ mx){
  const int d = blockIdx.x*64 + threadIdx.x;
  const int j = blockIdx.y;   // chunk
  const int b = blockIdx.z;
  float q[ND], w[ND], s[ND];
#pragma unroll
  for (int n=0;n<ND;n++){ q[n]=qp[d*ND+n]; w[n]=wp[d*ND+n]; s[n]=0.0f; }
  const float om = omega[d];
  const int l0 = j*128;
  int lw = l0 - 1024; if (lw < 0) lw = 0;   // q^1024 < 1e-20 at q<=0.95: exact to fp32
  const float* xc = xn + (long)b*DM + d;
  for (int l=lw;l<l0;l++){
    const float xv = xc[(long)l*(NB*DM)];
#pragma unroll
    for (int n=0;n<ND;n++) s[n] = fmaf(q[n], s[n], xv);
  }
  for (int l=l0;l<l0+128;l++){
    const float xv = xc[(long)l*(NB*DM)];
    float a = 0.0f;
#pragma unroll
    for (int n=0;n<ND;n++){ s[n] = fmaf(q[n], s[n], xv); a = fmaf(w[n], s[n], a); }
    mx[((long)l*NB + b)*DM + d] = (__bf16)silu_(a + xv*om);
  }
}

// ---------------- v (L*B,H) -> vT (B,H,L) ----------------
__global__ __launch_bounds__(256) void transpose_v(const __bf16* __restrict__ v, __bf16* __restrict__ vT){
  __shared__ __bf16 t[64][65];
  const int b = blockIdx.z;
  const int l0 = blockIdx.x*64, h0 = blockIdx.y*64;
  const int tx = threadIdx.x & 63, ty = threadIdx.x >> 6;
  for (int i=ty;i<64;i+=4) t[i][tx] = v[((long)(l0+i)*NB + b)*HD + h0 + tx];
  __syncthreads();
  for (int i=ty;i<64;i+=4) vT[((long)b*HD + h0+i)*LSEQ + l0 + tx] = t[tx][i];
}

// ---------------- q/k extension with fused rotary bias ----------------
// qx[b,l,0:128]=(z*g0+b0)/L, qx[...,128:256]=ra[l];  kx = [z*g1+b1, rb[l]]
__global__ __launch_bounds__(256) void qk_prep(const float* __restrict__ z, const float* __restrict__ qkg,
                                               const float* __restrict__ qkb, const float* __restrict__ ra,
                                               const float* __restrict__ rb, __bf16* __restrict__ qx,
                                               __bf16* __restrict__ kx){
  const int l = blockIdx.x, b = blockIdx.y, zi = threadIdx.x;
  float qv, kv;
  if (zi < ZD){
    const float zv = z[((long)l*NB+b)*ZD + zi];
    qv = (zv*qkg[zi] + qkb[zi]) * (1.0f/LSEQ);
    kv =  zv*qkg[ZD+zi] + qkb[ZD+zi];
  } else {
    const int i = zi - ZD;
    const int jf = i & 63;
    const float f = expf((float)jf * (-0.14391156831f));  // -ln(10000)/64
    const float ang = (float)l * f;
    const float sn = sinf(ang), cs = cosf(ang);
    if (i < 64){ qv = ra[i]*cs - ra[i+64]*sn; kv = rb[i]*cs - rb[i+64]*sn; }
    else       { qv = ra[i]*cs + ra[i-64]*sn; kv = rb[i]*cs + rb[i-64]*sn; }
  }
  const long o = ((long)b*LSEQ + l)*NEXTD + zi;
  qx[o] = (__bf16)qv;
  kx[o] = (__bf16)kv;
}

// ---------------- m97-style bf16 GEMM: C = A(M,K) * B(N,K)^T ----------------
// 128x128 tile, 4 waves, 4x4 16x16x32 frags/wave, BK=64, global_load_lds(16B),
// XOR chunk swizzle (applied on global fetch side) so ds_read_b128 is <=2-way.
// MODE: 0=v(silu+bias,bf16)  1=base 4-way split  2=laplace->S  3=*r->a3  4=final
template<int MODE>
__global__ __launch_bounds__(256) void gemm_bt(
    const __bf16* __restrict__ A, const __bf16* __restrict__ Bw,
    int K, long aBatch, long bBatch, const float* __restrict__ bias,
    void* __restrict__ o0, void* __restrict__ o1, void* __restrict__ o2, void* __restrict__ o3,
    const void* __restrict__ x0, const void* __restrict__ x1, const void* __restrict__ x2)
{
  __shared__ __align__(16) __bf16 As[128*64];
  __shared__ __align__(16) __bf16 Bs[128*64];
  const int tid = threadIdx.x;
  const int lane = tid & 63;
  const int wid = tid >> 6;
  const int bz = blockIdx.z;
  const long m0 = (long)blockIdx.x * 128;
  const long n0 = (long)blockIdx.y * 128;
  const __bf16* Ab = A + (long)bz * aBatch;
  const __bf16* Bb = Bw + (long)bz * bBatch;
  const int wm = wid & 1, wn = wid >> 1;
  const int lrow = lane >> 3;            // row within 8-row staging group
  const int gchunk = (lane & 7) ^ lrow;  // swizzled global 16B-chunk index

  f32x4 acc[4][4];
#pragma unroll
  for (int i=0;i<4;i++)
#pragma unroll
    for (int j=0;j<4;j++)
#pragma unroll
      for (int r=0;r<4;r++) acc[i][j][r] = 0.0f;

  for (int k0=0;k0<K;k0+=64){
    __syncthreads();
#pragma unroll
    for (int j=0;j<4;j++){
      const int g = j*4 + wid;           // 16 groups of 8 rows
      const long ar = m0 + g*8 + lrow;
      load_lds16(Ab + ar*(long)K + (k0 + gchunk*8), &As[g*512]);
      const long br = n0 + g*8 + lrow;
      load_lds16(Bb + br*(long)K + (k0 + gchunk*8), &Bs[g*512]);
    }
    __syncthreads();  // drains vmcnt(0): LDS ready
#pragma unroll
    for (int ks=0;ks<2;ks++){
      bf16x8 af[4], bfv[4];
      const int qd = (lane>>4) + ks*4;
#pragma unroll
      for (int i=0;i<4;i++){
        const int rowa = wm*64 + i*16 + (lane&15);
        af[i]  = *(const bf16x8*)&As[rowa*64 + ((qd ^ (rowa&7))<<3)];
        const int rowb = wn*64 + i*16 + (lane&15);
        bfv[i] = *(const bf16x8*)&Bs[rowb*64 + ((qd ^ (rowb&7))<<3)];
      }
#pragma unroll
      for (int i=0;i<4;i++)
#pragma unroll
        for (int j=0;j<4;j++)
          acc[i][j] = __builtin_amdgcn_mfma_f32_16x16x32_bf16(af[i], bfv[j], acc[i][j], 0, 0, 0);
    }
  }

  // epilogue: C[row= (lane>>4)*4+reg ][col= lane&15] per frag
#pragma unroll
  for (int i=0;i<4;i++){
    const long rbase = m0 + wm*64 + i*16 + ((lane>>4)<<2);
#pragma unroll
    for (int j=0;j<4;j++){
      const long col = n0 + wn*64 + j*16 + (lane&15);
#pragma unroll
      for (int r=0;r<4;r++){
        float c = acc[i][j][r];
        const long row = rbase + r;
        if (MODE==0){
          c = silu_(c + bias[col]);
          ((__bf16*)o0)[row*HD + col] = (__bf16)c;
        } else if (MODE==1){
          c += bias[col];
          if (col < DM)              ((float*)o0)[row*DM + col] = sigm(c);                       // u
          else if (col < DM+ZD)      ((float*)o1)[row*ZD + (col-DM)] = silu_(c);                 // z
          else if (col < DM+ZD+HD)   ((__bf16*)o2)[row*HD + (col-DM-ZD)] = (__bf16)silu_(c);     // r
          else                       ((float*)o3)[row*DM + (col-DM-ZD-HD)] = c;                  // hx
        } else if (MODE==2){
          ((__bf16*)o0)[(long)bz*LSEQ*LSEQ + row*LSEQ + col] = (__bf16)laplacef(c);
        } else if (MODE==3){
          const long idx = (row*NB + bz)*HD + col;
          const float rv = (float)((const __bf16*)x0)[idx];
          ((__bf16*)o0)[idx] = (__bf16)(c*rv);
        } else {
          c += bias[col];
          const long idx = row*DM + col;
          const float t = silu_(((const float*)x0)[idx] + c);   // silu(hx + h2 + bh)
          const float xv = ((const float*)x2)[idx];
          ((float*)o0)[idx] = xv + ((const float*)x1)[idx]*(t - xv);
        }
      }
    }
  }
}

extern "C" void kernel_launch(void* const* d_in, const int* in_sizes, int n_in,
                              void* d_out, int out_size, void* d_ws, size_t ws_size,
                              hipStream_t stream) {
  const float* x      = (const float*)d_in[0];
  const float* edelta = (const float*)d_in[1];
  const float* ealpha = (const float*)d_in[2];
  const float* ebeta  = (const float*)d_in[3];
  const float* egamma = (const float*)d_in[4];
  const float* eomega = (const float*)d_in[5];
  const float* lnw    = (const float*)d_in[6];
  const float* lnb    = (const float*)d_in[7];
  const float* Wv     = (const float*)d_in[8];
  const float* bv     = (const float*)d_in[9];
  const float* Wmx    = (const float*)d_in[10];
  const float* bmx    = (const float*)d_in[11];
  const float* Wh     = (const float*)d_in[12];
  const float* bh     = (const float*)d_in[13];
  const float* qkg    = (const float*)d_in[14];
  const float* qkb    = (const float*)d_in[15];
  const float* ralpha = (const float*)d_in[16];
  const float* rbeta  = (const float*)d_in[17];
  float* out = (float*)d_out;

  char* ws = (char*)d_ws;
  size_t off = 0;
  auto alloc = [&](size_t bytes) -> char* {
    char* p = ws + off; off = (off + bytes + 255) & ~(size_t)255; return p;
  };
  char* p_xnf  = alloc(33554432);  // xn f32 ; later aliased by S (bf16, 32MB)
  char* p_xnb  = alloc(16777216);  // xn bf16 ; later aliased by qx+kx (4MB+4MB)
  char* p_mx   = alloc(16777216);  // mx bf16
  char* p_wvb  = alloc(4194304);   // Wv bf16
  char* p_wmxb = alloc(8650752);   // Wmx bf16
  char* p_whb  = alloc(4194304);   // Wh bf16
  char* p_eq   = alloc(65536);     // ema q
  char* p_ew   = alloc(65536);     // ema w'
  char* p_v    = alloc(33554432);  // v bf16 ; later aliased by a3 (h*r, bf16)
  char* p_vT   = alloc(33554432);  // vT bf16 (B,H,L)
  char* p_u    = alloc(33554432);  // u f32
  char* p_z    = alloc(4194304);   // z f32
  char* p_r    = alloc(33554432);  // r bf16
  char* p_hx   = alloc(33554432);  // hx f32
  // total ~245 MB

  // weights -> bf16
  f2b<<<2048, 256, 0, stream>>>((const float4*)Wv,  (bf16x4*)p_wvb, 524288);
  f2b<<<4224, 256, 0, stream>>>((const float4*)Wmx, (bf16x4*)p_wmxb, 1081344);
  f2b<<<2048, 256, 0, stream>>>((const float4*)Wh,  (bf16x4*)p_whb, 524288);

  ema_params_k<<<64, 256, 0, stream>>>(edelta, ealpha, ebeta, egamma, (float*)p_eq, (float*)p_ew);
  ln_kernel<<<8192, 256, 0, stream>>>(x, lnw, lnb, (float*)p_xnf, (__bf16*)p_xnb);
  ema_kernel<<<dim3(16,16,4), 64, 0, stream>>>((const float*)p_xnf, (const float*)p_eq,
                                               (const float*)p_ew, eomega, (__bf16*)p_mx);

  // v = silu(xn @ Wv^T + bv)
  gemm_bt<0><<<dim3(64,16,1), 256, 0, stream>>>((const __bf16*)p_xnb, (const __bf16*)p_wvb,
      1024, 0, 0, bv, p_v, nullptr, nullptr, nullptr, nullptr, nullptr, nullptr);
  transpose_v<<<dim3(32,32,4), 256, 0, stream>>>((const __bf16*)p_v, (__bf16*)p_vT);

  // base = mx @ Wmx^T + bmx -> u / z / r / hx
  gemm_bt<1><<<dim3(64,33,1), 256, 0, stream>>>((const __bf16*)p_mx, (const __bf16*)p_wmxb,
      1024, 0, 0, bmx, p_u, p_z, p_r, p_hx, nullptr, nullptr, nullptr);

  __bf16* qx = (__bf16*)p_xnb;
  __bf16* kx = (__bf16*)(p_xnb + 4194304);
  qk_prep<<<dim3(2048,4), 256, 0, stream>>>((const float*)p_z, qkg, qkb, ralpha, rbeta, qx, kx);

  // S = laplace(qx @ kx^T)  (rotary bias fused via K-extension)
  __bf16* S = (__bf16*)p_xnf;
  gemm_bt<2><<<dim3(16,16,4), 256, 0, stream>>>(qx, kx,
      256, (long)LSEQ*NEXTD, (long)LSEQ*NEXTD, nullptr, S, nullptr, nullptr, nullptr,
      nullptr, nullptr, nullptr);

  // a3 = (S @ vT^T) * r
  __bf16* a3 = (__bf16*)p_v;
  gemm_bt<3><<<dim3(16,16,4), 256, 0, stream>>>(S, (const __bf16*)p_vT,
      2048, (long)LSEQ*LSEQ, (long)HD*LSEQ, nullptr, a3, nullptr, nullptr, nullptr,
      p_r, nullptr, nullptr);

  // out = x + u*(silu(hx + a3 @ Wh^T + bh) - x)
  gemm_bt<4><<<dim3(64,8,1), 256, 0, stream>>>(a3, (const __bf16*)p_whb,
      2048, 0, 0, bh, out, nullptr, nullptr, nullptr, p_hx, p_u, x);
}

// Round 2
// 618.304 us; speedup vs baseline: 1.4263x; 1.4263x over previous
//
#include <hip/hip_runtime.h>
#include <hip/hip_bf16.h>
#include <math.h>

#define LSEQ 2048
#define NB 4
#define DM 1024
#define ZD 128
#define HD 2048
#define ND 16
#define NEXTD 256
#define EMA_C 64
#define EMA_NCH 32

typedef __bf16 bf16x8 __attribute__((ext_vector_type(8)));
typedef __bf16 bf16x4 __attribute__((ext_vector_type(4)));
typedef float f32x4 __attribute__((ext_vector_type(4)));

__device__ __forceinline__ float sigm(float x){ return 1.0f/(1.0f+expf(-x)); }
__device__ __forceinline__ float silu_(float x){ return x/(1.0f+expf(-x)); }
__device__ __forceinline__ float laplacef(float x){ return 0.5f*(1.0f+erff((x-0.70710678f)*2.5066282746f)); }

__device__ __forceinline__ void load_lds16(const __bf16* g, __bf16* l){
  __builtin_amdgcn_global_load_lds((const __attribute__((address_space(1))) void*)g,
                                   (__attribute__((address_space(3))) void*)l, 16, 0, 0);
}

// ---------------- weight fp32 -> bf16 ----------------
__global__ __launch_bounds__(256) void f2b(const float4* __restrict__ in, bf16x4* __restrict__ out, int n4){
  const int i = blockIdx.x*256 + threadIdx.x;
  if (i < n4){
    float4 v = in[i];
    bf16x4 o; o[0]=(__bf16)v.x; o[1]=(__bf16)v.y; o[2]=(__bf16)v.z; o[3]=(__bf16)v.w;
    out[i] = o;
  }
}

// ---------------- LayerNorm: one block per row of 1024 ----------------
__global__ __launch_bounds__(256) void ln_kernel(const float* __restrict__ x, const float* __restrict__ w,
                                                 const float* __restrict__ b, float* __restrict__ xn,
                                                 __bf16* __restrict__ xnb){
  const long row = blockIdx.x;
  const int tid = threadIdx.x;
  float4 v = ((const float4*)(x + row*DM))[tid];
  float s = v.x+v.y+v.z+v.w;
  float ss = v.x*v.x+v.y*v.y+v.z*v.z+v.w*v.w;
#pragma unroll
  for (int o=32;o>0;o>>=1){ s += __shfl_down(s,o); ss += __shfl_down(ss,o); }
  __shared__ float red[8];
  __shared__ float mv[2];
  const int wid2 = tid>>6, lane = tid&63;
  if (lane==0){ red[wid2]=s; red[4+wid2]=ss; }
  __syncthreads();
  if (tid==0){
    float ts = red[0]+red[1]+red[2]+red[3];
    float tss = red[4]+red[5]+red[6]+red[7];
    float mean = ts*(1.0f/DM);
    float var = tss*(1.0f/DM) - mean*mean;
    mv[0]=mean; mv[1]=rsqrtf(var + 1e-5f);
  }
  __syncthreads();
  const float mean=mv[0], rs=mv[1];
  float4 wv = ((const float4*)w)[tid];
  float4 bv = ((const float4*)b)[tid];
  float4 o;
  o.x=(v.x-mean)*rs*wv.x+bv.x;
  o.y=(v.y-mean)*rs*wv.y+bv.y;
  o.z=(v.z-mean)*rs*wv.z+bv.z;
  o.w=(v.w-mean)*rs*wv.w+bv.w;
  ((float4*)(xn + row*DM))[tid]=o;
  bf16x4 ob; ob[0]=(__bf16)o.x; ob[1]=(__bf16)o.y; ob[2]=(__bf16)o.z; ob[3]=(__bf16)o.w;
  ((bf16x4*)(xnb + row*DM))[tid]=ob;
}

// ---------------- EMA parameter precompute: i = d*16+n ----------------
__global__ __launch_bounds__(256) void ema_params_k(const float* __restrict__ de, const float* __restrict__ al,
                                                    const float* __restrict__ be, const float* __restrict__ ga,
                                                    float* __restrict__ qo, float* __restrict__ wo,
                                                    float* __restrict__ qco){
  const int i = blockIdx.x*256 + threadIdx.x;  // exactly D*ND threads
  const float p = sigm(de[i]);
  const float q = 1.0f - p*sigm(al[i]);
  qo[i] = q;
  wo[i] = p*be[i]*ga[i]*0.25f;   // scale = sqrt(1/16)
  qco[i] = powf(q, (float)EMA_C); // chunk decay q^C
}

// ---------------- EMA pass A: per-chunk partial end-state (zero init) ----------------
__global__ __launch_bounds__(64) void ema_chunk_k(const float* __restrict__ xn, const float* __restrict__ qp,
                                                  float* __restrict__ E){
  const int d = blockIdx.x*64 + threadIdx.x;
  const int j = blockIdx.y, b = blockIdx.z;
  float q[ND], s[ND];
#pragma unroll
  for (int n=0;n<ND;n++){ q[n]=qp[d*ND+n]; s[n]=0.0f; }
  const float* xc = xn + (long)b*DM + d + (long)j*EMA_C*(NB*DM);
#pragma unroll
  for (int lt=0; lt<EMA_C; lt+=4){
    float xv[4];
#pragma unroll
    for (int u=0;u<4;u++) xv[u] = xc[(long)(lt+u)*(NB*DM)];
#pragma unroll
    for (int u=0;u<4;u++)
#pragma unroll
      for (int n=0;n<ND;n++) s[n] = fmaf(q[n], s[n], xv[u]);
  }
  float4* Eo = (float4*)(E + (((long)b*EMA_NCH + j)*DM + d)*ND);
#pragma unroll
  for (int n=0;n<4;n++) Eo[n] = make_float4(s[4*n], s[4*n+1], s[4*n+2], s[4*n+3]);
}

// ---------------- EMA pass B: serial scan over chunks (tiny) ----------------
// thread t = (b, d, n); Sinit[j] = state entering chunk j
__global__ __launch_bounds__(256) void ema_scan_k(const float* __restrict__ E, const float* __restrict__ qc,
                                                  float* __restrict__ Sinit){
  const int t = blockIdx.x*256 + threadIdx.x;   // 65536 threads
  const int b = t >> 14;
  const int rem = t & 16383;                    // d*ND + n
  const float q64 = qc[rem];
  float s = 0.0f;
  const long base = (long)b*EMA_NCH*16384 + rem;
  for (int j=0;j<EMA_NCH;j++){
    const long idx = base + (long)j*16384;
    Sinit[idx] = s;
    s = fmaf(q64, s, E[idx]);
  }
}

// ---------------- EMA pass C: outputs with exact initial state ----------------
__global__ __launch_bounds__(64) void ema_out_k(const float* __restrict__ xn, const float* __restrict__ qp,
                                                const float* __restrict__ wp, const float* __restrict__ omega,
                                                const float* __restrict__ Sinit, __bf16* __restrict__ mx){
  const int d = blockIdx.x*64 + threadIdx.x;
  const int j = blockIdx.y, b = blockIdx.z;
  float q[ND], w[ND], s[ND];
  const float4* Si = (const float4*)(Sinit + (((long)b*EMA_NCH + j)*DM + d)*ND);
#pragma unroll
  for (int n=0;n<4;n++){ float4 v=Si[n]; s[4*n]=v.x; s[4*n+1]=v.y; s[4*n+2]=v.z; s[4*n+3]=v.w; }
#pragma unroll
  for (int n=0;n<ND;n++){ q[n]=qp[d*ND+n]; w[n]=wp[d*ND+n]; }
  const float om = omega[d];
  const int l0 = j*EMA_C;
  const float* xc = xn + (long)b*DM + d;
#pragma unroll
  for (int lt=0; lt<EMA_C; lt+=4){
    float xv[4];
#pragma unroll
    for (int u=0;u<4;u++) xv[u] = xc[(long)(l0+lt+u)*(NB*DM)];
#pragma unroll
    for (int u=0;u<4;u++){
      float a = 0.0f;
#pragma unroll
      for (int n=0;n<ND;n++){ s[n] = fmaf(q[n], s[n], xv[u]); a = fmaf(w[n], s[n], a); }
      mx[((long)(l0+lt+u)*NB + b)*DM + d] = (__bf16)silu_(a + xv[u]*om);
    }
  }
}

// ---------------- v (L*B,H) -> vT (B,H,L) ----------------
__global__ __launch_bounds__(256) void transpose_v(const __bf16* __restrict__ v, __bf16* __restrict__ vT){
  __shared__ __bf16 t[64][65];
  const int b = blockIdx.z;
  const int l0 = blockIdx.x*64, h0 = blockIdx.y*64;
  const int tx = threadIdx.x & 63, ty = threadIdx.x >> 6;
  for (int i=ty;i<64;i+=4) t[i][tx] = v[((long)(l0+i)*NB + b)*HD + h0 + tx];
  __syncthreads();
  for (int i=ty;i<64;i+=4) vT[((long)b*HD + h0+i)*LSEQ + l0 + tx] = t[tx][i];
}

// ---------------- q/k extension with fused rotary bias ----------------
__global__ __launch_bounds__(256) void qk_prep(const float* __restrict__ z, const float* __restrict__ qkg,
                                               const float* __restrict__ qkb, const float* __restrict__ ra,
                                               const float* __restrict__ rb, __bf16* __restrict__ qx,
                                               __bf16* __restrict__ kx){
  const int l = blockIdx.x, b = blockIdx.y, zi = threadIdx.x;
  float qv, kv;
  if (zi < ZD){
    const float zv = z[((long)l*NB+b)*ZD + zi];
    qv = (zv*qkg[zi] + qkb[zi]) * (1.0f/LSEQ);
    kv =  zv*qkg[ZD+zi] + qkb[ZD+zi];
  } else {
    const int i = zi - ZD;
    const int jf = i & 63;
    const float f = expf((float)jf * (-0.14391156831f));  // -ln(10000)/64
    const float ang = (float)l * f;
    const float sn = sinf(ang), cs = cosf(ang);
    if (i < 64){ qv = ra[i]*cs - ra[i+64]*sn; kv = rb[i]*cs - rb[i+64]*sn; }
    else       { qv = ra[i]*cs + ra[i-64]*sn; kv = rb[i]*cs + rb[i-64]*sn; }
  }
  const long o = ((long)b*LSEQ + l)*NEXTD + zi;
  qx[o] = (__bf16)qv;
  kx[o] = (__bf16)kv;
}

// ---------------- m97-style bf16 GEMM: C = A(M,K) * B(N,K)^T ----------------
// MODE: 0=v(silu+bias,bf16)  1=base 4-way split  2=laplace->S  3=*r->a3  4=final
template<int MODE>
__global__ __launch_bounds__(256) void gemm_bt(
    const __bf16* __restrict__ A, const __bf16* __restrict__ Bw,
    int K, long aBatch, long bBatch, const float* __restrict__ bias,
    void* __restrict__ o0, void* __restrict__ o1, void* __restrict__ o2, void* __restrict__ o3,
    const void* __restrict__ x0, const void* __restrict__ x1, const void* __restrict__ x2)
{
  __shared__ __align__(16) __bf16 As[128*64];
  __shared__ __align__(16) __bf16 Bs[128*64];
  const int tid = threadIdx.x;
  const int lane = tid & 63;
  const int wid = tid >> 6;
  const int bz = blockIdx.z;
  const long m0 = (long)blockIdx.x * 128;
  const long n0 = (long)blockIdx.y * 128;
  const __bf16* Ab = A + (long)bz * aBatch;
  const __bf16* Bb = Bw + (long)bz * bBatch;
  const int wm = wid & 1, wn = wid >> 1;
  const int lrow = lane >> 3;            // row within 8-row staging group
  const int gchunk = (lane & 7) ^ lrow;  // swizzled global 16B-chunk index

  f32x4 acc[4][4];
#pragma unroll
  for (int i=0;i<4;i++)
#pragma unroll
    for (int j=0;j<4;j++)
#pragma unroll
      for (int r=0;r<4;r++) acc[i][j][r] = 0.0f;

  for (int k0=0;k0<K;k0+=64){
    __syncthreads();
#pragma unroll
    for (int j=0;j<4;j++){
      const int g = j*4 + wid;           // 16 groups of 8 rows
      const long ar = m0 + g*8 + lrow;
      load_lds16(Ab + ar*(long)K + (k0 + gchunk*8), &As[g*512]);
      const long br = n0 + g*8 + lrow;
      load_lds16(Bb + br*(long)K + (k0 + gchunk*8), &Bs[g*512]);
    }
    __syncthreads();  // drains vmcnt(0): LDS ready
#pragma unroll
    for (int ks=0;ks<2;ks++){
      bf16x8 af[4], bfv[4];
      const int qd = (lane>>4) + ks*4;
#pragma unroll
      for (int i=0;i<4;i++){
        const int rowa = wm*64 + i*16 + (lane&15);
        af[i]  = *(const bf16x8*)&As[rowa*64 + ((qd ^ (rowa&7))<<3)];
        const int rowb = wn*64 + i*16 + (lane&15);
        bfv[i] = *(const bf16x8*)&Bs[rowb*64 + ((qd ^ (rowb&7))<<3)];
      }
#pragma unroll
      for (int i=0;i<4;i++)
#pragma unroll
        for (int j=0;j<4;j++)
          acc[i][j] = __builtin_amdgcn_mfma_f32_16x16x32_bf16(af[i], bfv[j], acc[i][j], 0, 0, 0);
    }
  }

  // epilogue: C[row= (lane>>4)*4+reg ][col= lane&15] per frag
#pragma unroll
  for (int i=0;i<4;i++){
    const long rbase = m0 + wm*64 + i*16 + ((lane>>4)<<2);
#pragma unroll
    for (int j=0;j<4;j++){
      const long col = n0 + wn*64 + j*16 + (lane&15);
#pragma unroll
      for (int r=0;r<4;r++){
        float c = acc[i][j][r];
        const long row = rbase + r;
        if (MODE==0){
          c = silu_(c + bias[col]);
          ((__bf16*)o0)[row*HD + col] = (__bf16)c;
        } else if (MODE==1){
          c += bias[col];
          if (col < DM)              ((float*)o0)[row*DM + col] = sigm(c);                       // u
          else if (col < DM+ZD)      ((float*)o1)[row*ZD + (col-DM)] = silu_(c);                 // z
          else if (col < DM+ZD+HD)   ((__bf16*)o2)[row*HD + (col-DM-ZD)] = (__bf16)silu_(c);     // r
          else                       ((float*)o3)[row*DM + (col-DM-ZD-HD)] = c;                  // hx
        } else if (MODE==2){
          ((__bf16*)o0)[(long)bz*LSEQ*LSEQ + row*LSEQ + col] = (__bf16)laplacef(c);
        } else if (MODE==3){
          const long idx = (row*NB + bz)*HD + col;
          const float rv = (float)((const __bf16*)x0)[idx];
          ((__bf16*)o0)[idx] = (__bf16)(c*rv);
        } else {
          c += bias[col];
          const long idx = row*DM + col;
          const float t = silu_(((const float*)x0)[idx] + c);   // silu(hx + h2 + bh)
          const float xv = ((const float*)x2)[idx];
          ((float*)o0)[idx] = xv + ((const float*)x1)[idx]*(t - xv);
        }
      }
    }
  }
}

extern "C" void kernel_launch(void* const* d_in, const int* in_sizes, int n_in,
                              void* d_out, int out_size, void* d_ws, size_t ws_size,
                              hipStream_t stream) {
  const float* x      = (const float*)d_in[0];
  const float* edelta = (const float*)d_in[1];
  const float* ealpha = (const float*)d_in[2];
  const float* ebeta  = (const float*)d_in[3];
  const float* egamma = (const float*)d_in[4];
  const float* eomega = (const float*)d_in[5];
  const float* lnw    = (const float*)d_in[6];
  const float* lnb    = (const float*)d_in[7];
  const float* Wv     = (const float*)d_in[8];
  const float* bv     = (const float*)d_in[9];
  const float* Wmx    = (const float*)d_in[10];
  const float* bmx    = (const float*)d_in[11];
  const float* Wh     = (const float*)d_in[12];
  const float* bh     = (const float*)d_in[13];
  const float* qkg    = (const float*)d_in[14];
  const float* qkb    = (const float*)d_in[15];
  const float* ralpha = (const float*)d_in[16];
  const float* rbeta  = (const float*)d_in[17];
  float* out = (float*)d_out;

  char* ws = (char*)d_ws;
  size_t off = 0;
  auto alloc = [&](size_t bytes) -> char* {
    char* p = ws + off; off = (off + bytes + 255) & ~(size_t)255; return p;
  };
  char* p_xnf  = alloc(33554432);  // xn f32 ; later aliased by S (bf16, 32MB)
  char* p_xnb  = alloc(16777216);  // xn bf16 ; later aliased by qx+kx (4MB+4MB)
  char* p_mx   = alloc(16777216);  // mx bf16
  char* p_wvb  = alloc(4194304);   // Wv bf16
  char* p_wmxb = alloc(8650752);   // Wmx bf16
  char* p_whb  = alloc(4194304);   // Wh bf16
  char* p_eq   = alloc(65536);     // ema q
  char* p_ew   = alloc(65536);     // ema w'
  char* p_v    = alloc(33554432);  // v bf16 ; later aliased by a3 (h*r, bf16)
  char* p_vT   = alloc(33554432);  // vT bf16 (B,H,L)
  char* p_u    = alloc(33554432);  // u f32 ; EMA phase aliases: E (8MB) + Sinit (8MB)
  char* p_z    = alloc(4194304);   // z f32 ; EMA phase alias: q^C (64KB)
  char* p_r    = alloc(33554432);  // r bf16
  char* p_hx   = alloc(33554432);  // hx f32
  // total ~245 MB (unchanged from round 1)

  float* p_E  = (float*)p_u;                 // consumed before gemm<1> writes u
  float* p_si = (float*)(p_u + 8388608);
  float* p_qc = (float*)p_z;                 // consumed before gemm<1> writes z

  // weights -> bf16
  f2b<<<2048, 256, 0, stream>>>((const float4*)Wv,  (bf16x4*)p_wvb, 524288);
  f2b<<<4224, 256, 0, stream>>>((const float4*)Wmx, (bf16x4*)p_wmxb, 1081344);
  f2b<<<2048, 256, 0, stream>>>((const float4*)Wh,  (bf16x4*)p_whb, 524288);

  ema_params_k<<<64, 256, 0, stream>>>(edelta, ealpha, ebeta, egamma,
                                       (float*)p_eq, (float*)p_ew, p_qc);
  ln_kernel<<<8192, 256, 0, stream>>>(x, lnw, lnb, (float*)p_xnf, (__bf16*)p_xnb);

  // EMA: exact 3-pass chunked scan (C=64, 32 chunks)
  ema_chunk_k<<<dim3(16,EMA_NCH,4), 64, 0, stream>>>((const float*)p_xnf, (const float*)p_eq, p_E);
  ema_scan_k<<<256, 256, 0, stream>>>(p_E, p_qc, p_si);
  ema_out_k<<<dim3(16,EMA_NCH,4), 64, 0, stream>>>((const float*)p_xnf, (const float*)p_eq,
                                                   (const float*)p_ew, eomega, p_si, (__bf16*)p_mx);

  // v = silu(xn @ Wv^T + bv)
  gemm_bt<0><<<dim3(64,16,1), 256, 0, stream>>>((const __bf16*)p_xnb, (const __bf16*)p_wvb,
      1024, 0, 0, bv, p_v, nullptr, nullptr, nullptr, nullptr, nullptr, nullptr);
  transpose_v<<<dim3(32,32,4), 256, 0, stream>>>((const __bf16*)p_v, (__bf16*)p_vT);

  // base = mx @ Wmx^T + bmx -> u / z / r / hx
  gemm_bt<1><<<dim3(64,33,1), 256, 0, stream>>>((const __bf16*)p_mx, (const __bf16*)p_wmxb,
      1024, 0, 0, bmx, p_u, p_z, p_r, p_hx, nullptr, nullptr, nullptr);

  __bf16* qx = (__bf16*)p_xnb;
  __bf16* kx = (__bf16*)(p_xnb + 4194304);
  qk_prep<<<dim3(2048,4), 256, 0, stream>>>((const float*)p_z, qkg, qkb, ralpha, rbeta, qx, kx);

  // S = laplace(qx @ kx^T)  (rotary bias fused via K-extension)
  __bf16* S = (__bf16*)p_xnf;
  gemm_bt<2><<<dim3(16,16,4), 256, 0, stream>>>(qx, kx,
      256, (long)LSEQ*NEXTD, (long)LSEQ*NEXTD, nullptr, S, nullptr, nullptr, nullptr,
      nullptr, nullptr, nullptr);

  // a3 = (S @ vT^T) * r
  __bf16* a3 = (__bf16*)p_v;
  gemm_bt<3><<<dim3(16,16,4), 256, 0, stream>>>(S, (const __bf16*)p_vT,
      2048, (long)LSEQ*LSEQ, (long)HD*LSEQ, nullptr, a3, nullptr, nullptr, nullptr,
      p_r, nullptr, nullptr);

  // out = x + u*(silu(hx + a3 @ Wh^T + bh) - x)
  gemm_bt<4><<<dim3(64,8,1), 256, 0, stream>>>(a3, (const __bf16*)p_whb,
      2048, 0, 0, bh, out, nullptr, nullptr, nullptr, p_hx, p_u, x);
}

// Round 3
// 613.557 us; speedup vs baseline: 1.4374x; 1.0077x over previous
//
#include <hip/hip_runtime.h>
#include <hip/hip_bf16.h>
#include <math.h>

#define LSEQ 2048
#define NB 4
#define DM 1024
#define ZD 128
#define HD 2048
#define ND 16
#define NEXTD 256
#define EMA_C 64
#define EMA_NCH 32

typedef __bf16 bf16x8 __attribute__((ext_vector_type(8)));
typedef __bf16 bf16x4 __attribute__((ext_vector_type(4)));
typedef float f32x4 __attribute__((ext_vector_type(4)));

__device__ __forceinline__ float sigm(float x){ return 1.0f/(1.0f+expf(-x)); }
__device__ __forceinline__ float silu_(float x){ return x/(1.0f+expf(-x)); }
__device__ __forceinline__ float laplacef(float x){ return 0.5f*(1.0f+erff((x-0.70710678f)*2.5066282746f)); }

__device__ __forceinline__ void load_lds16(const __bf16* g, __bf16* l){
  __builtin_amdgcn_global_load_lds((const __attribute__((address_space(1))) void*)g,
                                   (__attribute__((address_space(3))) void*)l, 16, 0, 0);
}

// ---------------- weight fp32 -> bf16 ----------------
__global__ __launch_bounds__(256) void f2b(const float4* __restrict__ in, bf16x4* __restrict__ out, int n4){
  const int i = blockIdx.x*256 + threadIdx.x;
  if (i < n4){
    float4 v = in[i];
    bf16x4 o; o[0]=(__bf16)v.x; o[1]=(__bf16)v.y; o[2]=(__bf16)v.z; o[3]=(__bf16)v.w;
    out[i] = o;
  }
}

// ---------------- LayerNorm: one block per row of 1024 (bf16 out only) ----------------
__global__ __launch_bounds__(256) void ln_kernel(const float* __restrict__ x, const float* __restrict__ w,
                                                 const float* __restrict__ b, __bf16* __restrict__ xnb){
  const long row = blockIdx.x;
  const int tid = threadIdx.x;
  float4 v = ((const float4*)(x + row*DM))[tid];
  float s = v.x+v.y+v.z+v.w;
  float ss = v.x*v.x+v.y*v.y+v.z*v.z+v.w*v.w;
#pragma unroll
  for (int o=32;o>0;o>>=1){ s += __shfl_down(s,o); ss += __shfl_down(ss,o); }
  __shared__ float red[8];
  __shared__ float mv[2];
  const int wid2 = tid>>6, lane = tid&63;
  if (lane==0){ red[wid2]=s; red[4+wid2]=ss; }
  __syncthreads();
  if (tid==0){
    float ts = red[0]+red[1]+red[2]+red[3];
    float tss = red[4]+red[5]+red[6]+red[7];
    float mean = ts*(1.0f/DM);
    float var = tss*(1.0f/DM) - mean*mean;
    mv[0]=mean; mv[1]=rsqrtf(var + 1e-5f);
  }
  __syncthreads();
  const float mean=mv[0], rs=mv[1];
  float4 wv = ((const float4*)w)[tid];
  float4 bv = ((const float4*)b)[tid];
  bf16x4 ob;
  ob[0]=(__bf16)((v.x-mean)*rs*wv.x+bv.x);
  ob[1]=(__bf16)((v.y-mean)*rs*wv.y+bv.y);
  ob[2]=(__bf16)((v.z-mean)*rs*wv.z+bv.z);
  ob[3]=(__bf16)((v.w-mean)*rs*wv.w+bv.w);
  ((bf16x4*)(xnb + row*DM))[tid]=ob;
}

// ---------------- EMA parameter precompute: i = d*16+n ----------------
__global__ __launch_bounds__(256) void ema_params_k(const float* __restrict__ de, const float* __restrict__ al,
                                                    const float* __restrict__ be, const float* __restrict__ ga,
                                                    float* __restrict__ qo, float* __restrict__ wo,
                                                    float* __restrict__ qco){
  const int i = blockIdx.x*256 + threadIdx.x;
  const float p = sigm(de[i]);
  const float q = 1.0f - p*sigm(al[i]);
  qo[i] = q;
  wo[i] = p*be[i]*ga[i]*0.25f;
  qco[i] = powf(q, (float)EMA_C);
}

// ---------------- EMA pass A: per-chunk partial end-state (zero init) ----------------
__global__ __launch_bounds__(64) void ema_chunk_k(const __bf16* __restrict__ xn, const float* __restrict__ qp,
                                                  float* __restrict__ E){
  const int d = blockIdx.x*64 + threadIdx.x;
  const int j = blockIdx.y, b = blockIdx.z;
  float q[ND], s[ND];
#pragma unroll
  for (int n=0;n<ND;n++){ q[n]=qp[d*ND+n]; s[n]=0.0f; }
  const __bf16* xc = xn + (long)b*DM + d + (long)j*EMA_C*(NB*DM);
#pragma unroll
  for (int lt=0; lt<EMA_C; lt+=4){
    float xv[4];
#pragma unroll
    for (int u=0;u<4;u++) xv[u] = (float)xc[(long)(lt+u)*(NB*DM)];
#pragma unroll
    for (int u=0;u<4;u++)
#pragma unroll
      for (int n=0;n<ND;n++) s[n] = fmaf(q[n], s[n], xv[u]);
  }
  float4* Eo = (float4*)(E + (((long)b*EMA_NCH + j)*DM + d)*ND);
#pragma unroll
  for (int n=0;n<4;n++) Eo[n] = make_float4(s[4*n], s[4*n+1], s[4*n+2], s[4*n+3]);
}

// ---------------- EMA pass B: serial scan over chunks ----------------
__global__ __launch_bounds__(256) void ema_scan_k(const float* __restrict__ E, const float* __restrict__ qc,
                                                  float* __restrict__ Sinit){
  const int t = blockIdx.x*256 + threadIdx.x;
  const int b = t >> 14;
  const int rem = t & 16383;
  const float q64 = qc[rem];
  float s = 0.0f;
  const long base = (long)b*EMA_NCH*16384 + rem;
  for (int j=0;j<EMA_NCH;j++){
    const long idx = base + (long)j*16384;
    Sinit[idx] = s;
    s = fmaf(q64, s, E[idx]);
  }
}

// ---------------- EMA pass C: outputs with exact initial state ----------------
__global__ __launch_bounds__(64) void ema_out_k(const __bf16* __restrict__ xn, const float* __restrict__ qp,
                                                const float* __restrict__ wp, const float* __restrict__ omega,
                                                const float* __restrict__ Sinit, __bf16* __restrict__ mx){
  const int d = blockIdx.x*64 + threadIdx.x;
  const int j = blockIdx.y, b = blockIdx.z;
  float q[ND], w[ND], s[ND];
  const float4* Si = (const float4*)(Sinit + (((long)b*EMA_NCH + j)*DM + d)*ND);
#pragma unroll
  for (int n=0;n<4;n++){ float4 v=Si[n]; s[4*n]=v.x; s[4*n+1]=v.y; s[4*n+2]=v.z; s[4*n+3]=v.w; }
#pragma unroll
  for (int n=0;n<ND;n++){ q[n]=qp[d*ND+n]; w[n]=wp[d*ND+n]; }
  const float om = omega[d];
  const int l0 = j*EMA_C;
  const __bf16* xc = xn + (long)b*DM + d;
#pragma unroll
  for (int lt=0; lt<EMA_C; lt+=4){
    float xv[4];
#pragma unroll
    for (int u=0;u<4;u++) xv[u] = (float)xc[(long)(l0+lt+u)*(NB*DM)];
#pragma unroll
    for (int u=0;u<4;u++){
      float a = 0.0f;
#pragma unroll
      for (int n=0;n<ND;n++){ s[n] = fmaf(q[n], s[n], xv[u]); a = fmaf(w[n], s[n], a); }
      mx[((long)(l0+lt+u)*NB + b)*DM + d] = (__bf16)silu_(a + xv[u]*om);
    }
  }
}

// ---------------- v (L*B,H) -> vT (B,H,L) ----------------
__global__ __launch_bounds__(256) void transpose_v(const __bf16* __restrict__ v, __bf16* __restrict__ vT){
  __shared__ __bf16 t[64][65];
  const int b = blockIdx.z;
  const int l0 = blockIdx.x*64, h0 = blockIdx.y*64;
  const int tx = threadIdx.x & 63, ty = threadIdx.x >> 6;
  for (int i=ty;i<64;i+=4) t[i][tx] = v[((long)(l0+i)*NB + b)*HD + h0 + tx];
  __syncthreads();
  for (int i=ty;i<64;i+=4) vT[((long)b*HD + h0+i)*LSEQ + l0 + tx] = t[tx][i];
}

// ---------------- rotary extension cols [128,256) of qx/kx ----------------
__global__ __launch_bounds__(128) void rot_fill(const float* __restrict__ ra, const float* __restrict__ rb,
                                                __bf16* __restrict__ qx, __bf16* __restrict__ kx){
  const int l = blockIdx.x, b = blockIdx.y, i = threadIdx.x;
  const int jf = i & 63;
  const float f = expf((float)jf * (-0.14391156831f));
  const float ang = (float)l * f;
  const float sn = sinf(ang), cs = cosf(ang);
  float qv, kv;
  if (i < 64){ qv = ra[i]*cs - ra[i+64]*sn; kv = rb[i]*cs - rb[i+64]*sn; }
  else       { qv = ra[i]*cs + ra[i-64]*sn; kv = rb[i]*cs + rb[i-64]*sn; }
  const long o = ((long)b*LSEQ + l)*NEXTD + 128 + i;
  qx[o] = (__bf16)qv;
  kx[o] = (__bf16)kv;
}

// ---------------- m97-style bf16 GEMM: C = A(M,K) * B(N,K)^T ----------------
// LDS-staged vectorized epilogue (stage pitch 272 B, conflict-free).
// MODE: 0=v(silu,bf16) 1=base split(u/qk/r/hx) 2=laplace->S 3=*r->a3 4=final f32
template<int MODE>
__global__ __launch_bounds__(256) void gemm_bt(
    const __bf16* __restrict__ A, const __bf16* __restrict__ Bw,
    int K, long aBatch, long bBatch, const float* __restrict__ bias,
    void* __restrict__ o0, void* __restrict__ o1, void* __restrict__ o2, void* __restrict__ o3,
    const void* __restrict__ x0, const void* __restrict__ x1, const void* __restrict__ x2)
{
  __shared__ __align__(16) char smem_raw[34816];   // K-loop: As(16K)+Bs(16K); epilogue: 128x272B stage
  __bf16* As = (__bf16*)smem_raw;
  __bf16* Bs = (__bf16*)(smem_raw + 16384);
  const int tid = threadIdx.x;
  const int lane = tid & 63;
  const int wid = tid >> 6;
  const int bz = blockIdx.z;
  const long m0 = (long)blockIdx.x * 128;
  const long n0 = (long)blockIdx.y * 128;
  const __bf16* Ab = A + (long)bz * aBatch;
  const __bf16* Bb = Bw + (long)bz * bBatch;
  const int wm = wid & 1, wn = wid >> 1;
  const int lrow = lane >> 3;
  const int gchunk = (lane & 7) ^ lrow;

  f32x4 acc[4][4];
#pragma unroll
  for (int i=0;i<4;i++)
#pragma unroll
    for (int j=0;j<4;j++)
#pragma unroll
      for (int r=0;r<4;r++) acc[i][j][r] = 0.0f;

  for (int k0=0;k0<K;k0+=64){
    __syncthreads();
#pragma unroll
    for (int j=0;j<4;j++){
      const int g = j*4 + wid;
      const long ar = m0 + g*8 + lrow;
      load_lds16(Ab + ar*(long)K + (k0 + gchunk*8), &As[g*512]);
      const long br = n0 + g*8 + lrow;
      load_lds16(Bb + br*(long)K + (k0 + gchunk*8), &Bs[g*512]);
    }
    __syncthreads();
#pragma unroll
    for (int ks=0;ks<2;ks++){
      bf16x8 af[4], bfv[4];
      const int qd = (lane>>4) + ks*4;
#pragma unroll
      for (int i=0;i<4;i++){
        const int rowa = wm*64 + i*16 + (lane&15);
        af[i]  = *(const bf16x8*)&As[rowa*64 + ((qd ^ (rowa&7))<<3)];
        const int rowb = wn*64 + i*16 + (lane&15);
        bfv[i] = *(const bf16x8*)&Bs[rowb*64 + ((qd ^ (rowb&7))<<3)];
      }
#pragma unroll
      for (int i=0;i<4;i++)
#pragma unroll
        for (int j=0;j<4;j++)
          acc[i][j] = __builtin_amdgcn_mfma_f32_16x16x32_bf16(af[i], bfv[j], acc[i][j], 0, 0, 0);
    }
  }

  // ---------------- epilogue ----------------
  __bf16* st = (__bf16*)smem_raw;      // 128 rows x 136 bf16 (272 B pitch)
  float*  stf = (float*)smem_raw;      // 128 rows x 68 f32  (272 B pitch)
  const int quad = lane >> 4;
  const int row = tid >> 1, half = tid & 1;
  const long row_g = m0 + row;

  if (MODE == 4){
    // two f32 half-passes (cols p*64..p*64+63)
#pragma unroll
    for (int p=0;p<2;p++){
      __syncthreads();
      if (wn == p){
#pragma unroll
        for (int i=0;i<4;i++){
          const int tr0 = wm*64 + i*16 + quad*4;
#pragma unroll
          for (int j=0;j<4;j++){
            const int tc = j*16 + (lane&15);
            const float bb = bias[n0 + p*64 + tc];
#pragma unroll
            for (int r=0;r<4;r++) stf[(tr0+r)*68 + tc] = acc[i][j][r] + bb;
          }
        }
      }
      __syncthreads();
#pragma unroll
      for (int k=0;k<8;k++){
        f32x4 c4 = *(const f32x4*)&stf[row*68 + half*32 + k*4];
        const long cg = n0 + p*64 + half*32 + k*4;
        const long idx = row_g*DM + cg;
        bf16x4 h4 = *(const bf16x4*)((const __bf16*)x0 + idx);
        bf16x4 u4 = *(const bf16x4*)((const __bf16*)x1 + idx);
        float4 xv = *(const float4*)((const float*)x2 + idx);
        float4 o;
        o.x = xv.x + (float)u4[0]*(silu_((float)h4[0]+c4[0]) - xv.x);
        o.y = xv.y + (float)u4[1]*(silu_((float)h4[1]+c4[1]) - xv.y);
        o.z = xv.z + (float)u4[2]*(silu_((float)h4[2]+c4[2]) - xv.z);
        o.w = xv.w + (float)u4[3]*(silu_((float)h4[3]+c4[3]) - xv.w);
        *(float4*)((float*)o0 + idx) = o;
      }
    }
    return;
  }

  if (MODE == 1 && n0 == DM){
    // q/k block: two bf16 passes (qv then kv) from the same accumulators
    const float* qkg = (const float*)x0;
    const float* qkb = (const float*)x1;
    __bf16* qx = (__bf16*)o3;
    __bf16* kx = (__bf16*)x2;
#pragma unroll
    for (int pass=0; pass<2; pass++){
      __syncthreads();
#pragma unroll
      for (int i=0;i<4;i++){
        const int tr0 = wm*64 + i*16 + quad*4;
#pragma unroll
        for (int j=0;j<4;j++){
          const int tc = wn*64 + j*16 + (lane&15);   // zi 0..127
          const float bb = bias[DM + tc];
          const float g = pass ? qkg[ZD+tc] : qkg[tc];
          const float be = pass ? qkb[ZD+tc] : qkb[tc];
          const float sc = pass ? 1.0f : (1.0f/LSEQ);
#pragma unroll
          for (int r=0;r<4;r++){
            const float s = silu_(acc[i][j][r] + bb);
            st[(tr0+r)*136 + tc] = (__bf16)((s*g + be)*sc);
          }
        }
      }
      __syncthreads();
      __bf16* dst = pass ? kx : qx;
      const long l = row_g >> 2, b = row_g & 3;
      const long base = (b*LSEQ + l)*NEXTD;
#pragma unroll
      for (int k=0;k<8;k++){
        bf16x8 vv = *(const bf16x8*)&st[row*136 + half*64 + k*8];
        *(bf16x8*)(dst + base + half*64 + k*8) = vv;
      }
    }
    return;
  }

  // generic single bf16-tile staging
  __syncthreads();
#pragma unroll
  for (int i=0;i<4;i++){
    const int tr0 = wm*64 + i*16 + quad*4;
#pragma unroll
    for (int j=0;j<4;j++){
      const int tc = wn*64 + j*16 + (lane&15);
      const long col = n0 + tc;
      float bb = 0.0f;
      if (MODE==0 || MODE==1) bb = bias[col];
#pragma unroll
      for (int r=0;r<4;r++){
        float c = acc[i][j][r] + bb;
        if (MODE==0) c = silu_(c);
        else if (MODE==1){ c = (col < DM) ? sigm(c) : ((col < DM+ZD+HD) ? silu_(c) : c); }
        else if (MODE==2) c = laplacef(c);
        st[(tr0+r)*136 + tc] = (__bf16)c;
      }
    }
  }
  __syncthreads();

  __bf16* dst; long ld, coff;
  if (MODE==0){ dst = (__bf16*)o0; ld = HD; coff = n0; }
  else if (MODE==1){
    if (n0 < DM)            { dst = (__bf16*)o0; ld = DM; coff = n0; }          // u
    else if (n0 < DM+ZD+HD) { dst = (__bf16*)o1; ld = HD; coff = n0-DM-ZD; }    // r
    else                    { dst = (__bf16*)o2; ld = DM; coff = n0-DM-ZD-HD; } // hx
  }
  else if (MODE==2){ dst = (__bf16*)o0 + (long)bz*LSEQ*LSEQ; ld = LSEQ; coff = n0; }
  else { dst = (__bf16*)o0; ld = HD; coff = n0; }  // MODE 3 (addr adjusted below)

  if (MODE==3){
    const __bf16* rp = (const __bf16*)x0;
    const long base = (row_g*NB + bz)*HD + coff;
#pragma unroll
    for (int k=0;k<8;k++){
      bf16x8 vv = *(const bf16x8*)&st[row*136 + half*64 + k*8];
      bf16x8 rv = *(const bf16x8*)(rp + base + half*64 + k*8);
      bf16x8 ov;
#pragma unroll
      for (int e=0;e<8;e++) ov[e] = (__bf16)((float)vv[e]*(float)rv[e]);
      *(bf16x8*)((__bf16*)o0 + base + half*64 + k*8) = ov;
    }
  } else {
    const long base = row_g*ld + coff;
#pragma unroll
    for (int k=0;k<8;k++){
      bf16x8 vv = *(const bf16x8*)&st[row*136 + half*64 + k*8];
      *(bf16x8*)(dst + base + half*64 + k*8) = vv;
    }
  }
}

extern "C" void kernel_launch(void* const* d_in, const int* in_sizes, int n_in,
                              void* d_out, int out_size, void* d_ws, size_t ws_size,
                              hipStream_t stream) {
  const float* x      = (const float*)d_in[0];
  const float* edelta = (const float*)d_in[1];
  const float* ealpha = (const float*)d_in[2];
  const float* ebeta  = (const float*)d_in[3];
  const float* egamma = (const float*)d_in[4];
  const float* eomega = (const float*)d_in[5];
  const float* lnw    = (const float*)d_in[6];
  const float* lnb    = (const float*)d_in[7];
  const float* Wv     = (const float*)d_in[8];
  const float* bv     = (const float*)d_in[9];
  const float* Wmx    = (const float*)d_in[10];
  const float* bmx    = (const float*)d_in[11];
  const float* Wh     = (const float*)d_in[12];
  const float* bh     = (const float*)d_in[13];
  const float* qkg    = (const float*)d_in[14];
  const float* qkb    = (const float*)d_in[15];
  const float* ralpha = (const float*)d_in[16];
  const float* rbeta  = (const float*)d_in[17];
  float* out = (float*)d_out;

  char* ws = (char*)d_ws;
  size_t off = 0;
  auto alloc = [&](size_t bytes) -> char* {
    char* p = ws + off; off = (off + bytes + 255) & ~(size_t)255; return p;
  };
  char* p_S    = alloc(33554432);  // S bf16 (4x2048x2048)
  char* p_xnb  = alloc(16777216);  // xn bf16 ; later aliased by qx(4MB)+kx(4MB)
  char* p_mx   = alloc(16777216);  // mx bf16
  char* p_wvb  = alloc(4194304);   // Wv bf16
  char* p_wmxb = alloc(8650752);   // Wmx bf16
  char* p_whb  = alloc(4194304);   // Wh bf16
  char* p_eq   = alloc(65536);     // ema q
  char* p_ew   = alloc(65536);     // ema w'
  char* p_qc   = alloc(65536);     // ema q^C
  char* p_v    = alloc(33554432);  // v bf16 ; later aliased by a3 (h*r, bf16)
  char* p_vT   = alloc(33554432);  // vT bf16 (B,H,L)
  char* p_u    = alloc(16777216);  // u bf16 ; EMA phase aliases: E(8MB)+Sinit(8MB)
  char* p_r    = alloc(33554432);  // r bf16
  char* p_hx   = alloc(16777216);  // hx bf16

  float* p_E  = (float*)p_u;                 // consumed before gemm<1> writes u
  float* p_si = (float*)(p_u + 8388608);

  // weights -> bf16
  f2b<<<2048, 256, 0, stream>>>((const float4*)Wv,  (bf16x4*)p_wvb, 524288);
  f2b<<<4224, 256, 0, stream>>>((const float4*)Wmx, (bf16x4*)p_wmxb, 1081344);
  f2b<<<2048, 256, 0, stream>>>((const float4*)Wh,  (bf16x4*)p_whb, 524288);

  ema_params_k<<<64, 256, 0, stream>>>(edelta, ealpha, ebeta, egamma,
                                       (float*)p_eq, (float*)p_ew, (float*)p_qc);
  ln_kernel<<<8192, 256, 0, stream>>>(x, lnw, lnb, (__bf16*)p_xnb);

  // EMA: exact 3-pass chunked scan (C=64, 32 chunks), bf16 input
  ema_chunk_k<<<dim3(16,EMA_NCH,4), 64, 0, stream>>>((const __bf16*)p_xnb, (const float*)p_eq, p_E);
  ema_scan_k<<<256, 256, 0, stream>>>(p_E, (const float*)p_qc, p_si);
  ema_out_k<<<dim3(16,EMA_NCH,4), 64, 0, stream>>>((const __bf16*)p_xnb, (const float*)p_eq,
                                                   (const float*)p_ew, eomega, p_si, (__bf16*)p_mx);

  // v = silu(xn @ Wv^T + bv)
  gemm_bt<0><<<dim3(64,16,1), 256, 0, stream>>>((const __bf16*)p_xnb, (const __bf16*)p_wvb,
      1024, 0, 0, bv, p_v, nullptr, nullptr, nullptr, nullptr, nullptr, nullptr);
  transpose_v<<<dim3(32,32,4), 256, 0, stream>>>((const __bf16*)p_v, (__bf16*)p_vT);

  // base = mx @ Wmx^T + bmx -> u / (qx,kx) / r / hx   (z never materialized)
  __bf16* qx = (__bf16*)p_xnb;
  __bf16* kx = (__bf16*)(p_xnb + 4194304);
  gemm_bt<1><<<dim3(64,33,1), 256, 0, stream>>>((const __bf16*)p_mx, (const __bf16*)p_wmxb,
      1024, 0, 0, bmx, p_u, p_r, p_hx, qx, qkg, qkb, kx);
  rot_fill<<<dim3(LSEQ,NB), 128, 0, stream>>>(ralpha, rbeta, qx, kx);

  // S = laplace(qx @ kx^T)  (rotary bias fused via K-extension)
  __bf16* S = (__bf16*)p_S;
  gemm_bt<2><<<dim3(16,16,4), 256, 0, stream>>>(qx, kx,
      256, (long)LSEQ*NEXTD, (long)LSEQ*NEXTD, nullptr, S, nullptr, nullptr, nullptr,
      nullptr, nullptr, nullptr);

  // a3 = (S @ vT^T) * r
  __bf16* a3 = (__bf16*)p_v;
  gemm_bt<3><<<dim3(16,16,4), 256, 0, stream>>>(S, (const __bf16*)p_vT,
      2048, (long)LSEQ*LSEQ, (long)HD*LSEQ, nullptr, a3, nullptr, nullptr, nullptr,
      p_r, nullptr, nullptr);

  // out = x + u*(silu(hx + a3 @ Wh^T + bh) - x)
  gemm_bt<4><<<dim3(64,8,1), 256, 0, stream>>>(a3, (const __bf16*)p_whb,
      2048, 0, 0, bh, out, nullptr, nullptr, nullptr, p_hx, p_u, x);
}